// Round 8
// baseline (615.375 us; speedup 1.0000x reference)
//
#include <hip/hip_runtime.h>
#include <stdint.h>
#include <math.h>

#define N_NODES 100000
#define N_EDGES 1600000
#define IN_DIM 128
#define HID 256
#define N_CLS 40
#define NBKT 391                 // buckets of 256 dst nodes
#define NPB 391                  // edge partition blocks: ceil(1.6M/4096)

typedef __attribute__((ext_vector_type(8))) short short8;
typedef __attribute__((ext_vector_type(4))) float f32x4;

__device__ __forceinline__ unsigned short f2bf(float f) {
  unsigned b = __float_as_uint(f);
  b += 0x7fffu + ((b >> 16) & 1u);   // round-to-nearest-even
  return (unsigned short)(b >> 16);
}
__device__ __forceinline__ float bflo(unsigned u) { return __uint_as_float(u << 16); }
__device__ __forceinline__ float bfhi(unsigned u) { return __uint_as_float(u & 0xffff0000u); }

__device__ __forceinline__ int load_idx(const void* eidx, int flag, size_t pos) {
  return flag ? (int)((const long long*)eidx)[pos] : ((const int*)eidx)[pos];
}

// ---------------------------------------------------------------------------
// detect edge_index dtype + zero bucket histogram. One block.
// ---------------------------------------------------------------------------
__global__ __launch_bounds__(512) void k_pre0(const unsigned int* __restrict__ ew,
                                              int* __restrict__ flag,
                                              int* __restrict__ hist) {
  int t = threadIdx.x;
  for (int k = t; k < NBKT; k += 512) hist[k] = 0;
  __shared__ unsigned int sh[512];
  unsigned int v = 0;
  for (int k = t; k < 4096; k += 512) v |= ew[2 * k + 1];
  sh[t] = v;
  __syncthreads();
  for (int s = 256; s > 0; s >>= 1) {
    if (t < s) sh[t] |= sh[t + s];
    __syncthreads();
  }
  if (t == 0) flag[0] = (sh[0] == 0u) ? 1 : 0;
}

// bucket histogram over dst (bucket = dst>>8), LDS-aggregated
__global__ __launch_bounds__(256) void k_hist(const void* __restrict__ eidx,
                                              const int* __restrict__ flagp,
                                              int* __restrict__ hist) {
  __shared__ int lh[NBKT];
  int t = threadIdx.x;
  for (int k = t; k < NBKT; k += 256) lh[k] = 0;
  __syncthreads();
  int flag = flagp[0];
  int base = blockIdx.x * 4096;
#pragma unroll
  for (int j = 0; j < 16; j++) {
    int e = base + j * 256 + t;
    if (e < N_EDGES) {
      int d = load_idx(eidx, flag, (size_t)N_EDGES + e);
      atomicAdd(&lh[d >> 8], 1);
    }
  }
  __syncthreads();
  for (int k = t; k < NBKT; k += 256) {
    int c = lh[k];
    if (c) atomicAdd(&hist[k], c);
  }
}

// exclusive scan of buckets -> bucket_start[392], init bucket_cursor
__global__ __launch_bounds__(512) void k_bscan(const int* __restrict__ hist,
                                               int* __restrict__ bucket_start,
                                               int* __restrict__ bucket_cursor) {
  __shared__ int sh[512];
  int t = threadIdx.x;
  int v = (t < NBKT) ? hist[t] : 0;
  sh[t] = v;
  __syncthreads();
  for (int off = 1; off < 512; off <<= 1) {
    int u = (t >= off) ? sh[t - off] : 0;
    __syncthreads();
    sh[t] += u;
    __syncthreads();
  }
  if (t < NBKT) {
    bucket_start[t + 1] = sh[t];
    bucket_cursor[t] = sh[t] - v;
  }
  if (t == 0) bucket_start[0] = 0;
}

// partition edges into bucket-segmented (src,dst) pairs
__global__ __launch_bounds__(256) void k_part(const void* __restrict__ eidx,
                                              const int* __restrict__ flagp,
                                              int* __restrict__ bucket_cursor,
                                              uint2* __restrict__ bpairs) {
  __shared__ int lcur[NBKT];
  int t = threadIdx.x;
  for (int k = t; k < NBKT; k += 256) lcur[k] = 0;
  __syncthreads();
  int flag = flagp[0];
  int base = blockIdx.x * 4096;
#pragma unroll
  for (int j = 0; j < 16; j++) {
    int e = base + j * 256 + t;
    if (e < N_EDGES) {
      int d = load_idx(eidx, flag, (size_t)N_EDGES + e);
      atomicAdd(&lcur[d >> 8], 1);
    }
  }
  __syncthreads();
  for (int k = t; k < NBKT; k += 256) {
    int c = lcur[k];
    int g = c ? atomicAdd(&bucket_cursor[k], c) : 0;
    lcur[k] = g;
  }
  __syncthreads();
#pragma unroll
  for (int j = 0; j < 16; j++) {
    int e = base + j * 256 + t;
    if (e < N_EDGES) {
      int s = load_idx(eidx, flag, e);
      int d = load_idx(eidx, flag, (size_t)N_EDGES + e);
      int p = atomicAdd(&lcur[d >> 8], 1);
      bpairs[p] = make_uint2((unsigned)s, (unsigned)d);
    }
  }
}

// per-bucket finalize: local deg -> row_start + dinv + csr placement
__global__ __launch_bounds__(256) void k_bsort(const uint2* __restrict__ bpairs,
                                               const int* __restrict__ bucket_start,
                                               int* __restrict__ row_start,
                                               float* __restrict__ dinv,
                                               int* __restrict__ csr_src) {
  __shared__ int ldeg[256], lsum[256], lcur[256];
  int b = blockIdx.x, t = threadIdx.x;
  int d0 = b << 8;
  int nd = min(256, N_NODES - d0);
  int base = bucket_start[b];
  int n = bucket_start[b + 1] - base;
  ldeg[t] = 0;
  __syncthreads();
  for (int i = t; i < n; i += 256) {
    uint2 p = bpairs[base + i];
    atomicAdd(&ldeg[p.y - d0], 1);
  }
  __syncthreads();
  lsum[t] = ldeg[t];
  __syncthreads();
  for (int off = 1; off < 256; off <<= 1) {
    int v = (t >= off) ? lsum[t - off] : 0;
    __syncthreads();
    lsum[t] += v;
    __syncthreads();
  }
  int excl = lsum[t] - ldeg[t];
  if (t < nd) {
    row_start[d0 + t] = base + excl;
    dinv[d0 + t] = rsqrtf((float)(ldeg[t] + 1));
  }
  lcur[t] = base + excl;
  __syncthreads();
  for (int i = t; i < n; i += 256) {
    uint2 p = bpairs[base + i];
    int pos = atomicAdd(&lcur[p.y - d0], 1);
    csr_src[pos] = (int)p.x;
  }
  if (b == 0 && t == 0) row_start[N_NODES] = N_EDGES;
}

// ---------------------------------------------------------------------------
// weight prep: transpose + bf16
// ---------------------------------------------------------------------------
__global__ __launch_bounds__(256) void k_wprep(const float* __restrict__ W1,
                                               const float* __restrict__ W2,
                                               const float* __restrict__ W3,
                                               unsigned short* __restrict__ T1,
                                               unsigned short* __restrict__ T2,
                                               unsigned short* __restrict__ T3) {
  int idx = blockIdx.x * 256 + threadIdx.x;
  if (idx < 32768) {
    int n = idx >> 7, k = idx & 127;
    T1[idx] = f2bf(W1[(size_t)k * HID + n]);
  } else if (idx < 98304) {
    int j = idx - 32768;
    int n = j >> 8, k = j & 255;
    T2[j] = f2bf(W2[(size_t)k * HID + n]);
  } else if (idx < 131072) {
    int j = idx - 98304;
    int n = j >> 8, k = j & 255;
    T3[j] = f2bf((n < N_CLS) ? W3[(size_t)k * N_CLS + n] : 0.f);
  }
}

// ---------------------------------------------------------------------------
// quantize x: fp32 [N][128] -> signed int8 [N][64] ushort-packed, per-row scale
// folded into sw_x[i] = dinv[i] * scale_i. One wave per row.
// ---------------------------------------------------------------------------
__global__ __launch_bounds__(256) void k_qx(const float* __restrict__ x,
                                            const float* __restrict__ dinv,
                                            unsigned short* __restrict__ xq,
                                            float* __restrict__ sw_x) {
  int node = (blockIdx.x << 2) + (threadIdx.x >> 6);
  int lane = threadIdx.x & 63;
  if (node >= N_NODES) return;
  float2 v = ((const float2*)x)[(size_t)node * 64 + lane];
  float m = fmaxf(fabsf(v.x), fabsf(v.y));
  for (int off = 32; off; off >>= 1) m = fmaxf(m, __shfl_down(m, off));
  m = __shfl(m, 0);
  float inv = (m > 0.f) ? 127.f / m : 0.f;
  int q0 = __float2int_rn(v.x * inv);
  int q1 = __float2int_rn(v.y * inv);
  xq[(size_t)node * 64 + lane] = (unsigned short)((q0 & 0xff) | ((q1 & 0xff) << 8));
  if (lane == 0) sw_x[node] = dinv[node] * ((m > 0.f) ? m / 127.f : 0.f);
}

// ---------------------------------------------------------------------------
// quantize h1: bf16 [N][256] (>=0 after relu) -> uint8 [N][64] uint-packed,
// per-row scale folded into sw_h[i] = dinv[i] * scale_i. One wave per row.
// ---------------------------------------------------------------------------
__global__ __launch_bounds__(256) void k_qh(const uint2* __restrict__ h1,  // [N][64]
                                            const float* __restrict__ dinv,
                                            unsigned* __restrict__ hq,
                                            float* __restrict__ sw_h) {
  int node = (blockIdx.x << 2) + (threadIdx.x >> 6);
  int lane = threadIdx.x & 63;
  if (node >= N_NODES) return;
  uint2 v = h1[(size_t)node * 64 + lane];
  float b0 = bflo(v.x), b1 = bfhi(v.x), b2 = bflo(v.y), b3 = bfhi(v.y);
  float m = fmaxf(fmaxf(b0, b1), fmaxf(b2, b3));
  for (int off = 32; off; off >>= 1) m = fmaxf(m, __shfl_down(m, off));
  m = __shfl(m, 0);
  float inv = (m > 0.f) ? 255.f / m : 0.f;
  unsigned q0 = (unsigned)__float2int_rn(b0 * inv);
  unsigned q1 = (unsigned)__float2int_rn(b1 * inv);
  unsigned q2 = (unsigned)__float2int_rn(b2 * inv);
  unsigned q3 = (unsigned)__float2int_rn(b3 * inv);
  hq[(size_t)node * 64 + lane] = q0 | (q1 << 8) | (q2 << 16) | (q3 << 24);
  if (lane == 0) sw_h[node] = dinv[node] * ((m > 0.f) ? m / 255.f : 0.f);
}

// ---------------------------------------------------------------------------
// int8 gather aggregation, 256-dim: 1 wave/node, 4 uint8/lane (1 uint),
// row = 256B = 2 lines. a = sw[node]*q_node + sum sw[s]*q_s ; out = d*a (bf16)
// ---------------------------------------------------------------------------
__device__ __forceinline__ void up4u(unsigned v, float w,
                                     float& a0, float& a1, float& a2, float& a3) {
  a0 = fmaf((float)(v & 0xffu), w, a0);
  a1 = fmaf((float)((v >> 8) & 0xffu), w, a1);
  a2 = fmaf((float)((v >> 16) & 0xffu), w, a2);
  a3 = fmaf((float)(v >> 24), w, a3);
}

__global__ __launch_bounds__(256) void k_agg256i(const unsigned* __restrict__ tbl,  // [N][64]
                                                 uint2* __restrict__ out,           // [N][64]
                                                 const float* __restrict__ dinv,
                                                 const float* __restrict__ sw,
                                                 const int* __restrict__ row_start,
                                                 const int* __restrict__ csr_src) {
  int node = (blockIdx.x << 2) + (threadIdx.x >> 6);
  int lane = threadIdx.x & 63;
  if (node >= N_NODES) return;
  const unsigned* col = tbl + lane;
  float d = dinv[node];
  float ws = sw[node];
  unsigned v0 = col[(size_t)node * 64];
  float a0 = 0.f, a1 = 0.f, a2 = 0.f, a3 = 0.f;
  up4u(v0, ws, a0, a1, a2, a3);
  int e = row_start[node], e1 = row_start[node + 1];
  for (; e + 4 <= e1; e += 4) {
    int i0 = __builtin_nontemporal_load(&csr_src[e]);
    int i1 = __builtin_nontemporal_load(&csr_src[e + 1]);
    int i2 = __builtin_nontemporal_load(&csr_src[e + 2]);
    int i3 = __builtin_nontemporal_load(&csr_src[e + 3]);
    float w0 = sw[i0], w1 = sw[i1], w2 = sw[i2], w3 = sw[i3];
    unsigned r0 = col[(size_t)i0 * 64];
    unsigned r1 = col[(size_t)i1 * 64];
    unsigned r2 = col[(size_t)i2 * 64];
    unsigned r3 = col[(size_t)i3 * 64];
    up4u(r0, w0, a0, a1, a2, a3);
    up4u(r1, w1, a0, a1, a2, a3);
    up4u(r2, w2, a0, a1, a2, a3);
    up4u(r3, w3, a0, a1, a2, a3);
  }
  for (; e < e1; e++) {
    int i0 = __builtin_nontemporal_load(&csr_src[e]);
    float w0 = sw[i0];
    unsigned r0 = col[(size_t)i0 * 64];
    up4u(r0, w0, a0, a1, a2, a3);
  }
  a0 *= d; a1 *= d; a2 *= d; a3 *= d;
  uint2 o;
  o.x = f2bf(a0) | ((unsigned)f2bf(a1) << 16);
  o.y = f2bf(a2) | ((unsigned)f2bf(a3) << 16);
  out[(size_t)node * 64 + lane] = o;
}

// int8 gather aggregation, 128-dim: 2 int8/lane (ushort), row = 128B = 1 line.
__global__ __launch_bounds__(256) void k_agg128i(const unsigned short* __restrict__ tbl,
                                                 unsigned* __restrict__ out,  // [N][64]
                                                 const float* __restrict__ dinv,
                                                 const float* __restrict__ sw,
                                                 const int* __restrict__ row_start,
                                                 const int* __restrict__ csr_src) {
  int node = (blockIdx.x << 2) + (threadIdx.x >> 6);
  int lane = threadIdx.x & 63;
  if (node >= N_NODES) return;
  const unsigned short* col = tbl + lane;
  float d = dinv[node];
  float ws = sw[node];
  unsigned short v0 = col[(size_t)node * 64];
  float a0 = (float)(signed char)(v0 & 0xff) * ws;
  float a1 = (float)(signed char)(v0 >> 8) * ws;
  int e = row_start[node], e1 = row_start[node + 1];
  for (; e + 4 <= e1; e += 4) {
    int i0 = __builtin_nontemporal_load(&csr_src[e]);
    int i1 = __builtin_nontemporal_load(&csr_src[e + 1]);
    int i2 = __builtin_nontemporal_load(&csr_src[e + 2]);
    int i3 = __builtin_nontemporal_load(&csr_src[e + 3]);
    float w0 = sw[i0], w1 = sw[i1], w2 = sw[i2], w3 = sw[i3];
    unsigned short r0 = col[(size_t)i0 * 64];
    unsigned short r1 = col[(size_t)i1 * 64];
    unsigned short r2 = col[(size_t)i2 * 64];
    unsigned short r3 = col[(size_t)i3 * 64];
    a0 = fmaf((float)(signed char)(r0 & 0xff), w0, a0);
    a1 = fmaf((float)(signed char)(r0 >> 8), w0, a1);
    a0 = fmaf((float)(signed char)(r1 & 0xff), w1, a0);
    a1 = fmaf((float)(signed char)(r1 >> 8), w1, a1);
    a0 = fmaf((float)(signed char)(r2 & 0xff), w2, a0);
    a1 = fmaf((float)(signed char)(r2 >> 8), w2, a1);
    a0 = fmaf((float)(signed char)(r3 & 0xff), w3, a0);
    a1 = fmaf((float)(signed char)(r3 >> 8), w3, a1);
  }
  for (; e < e1; e++) {
    int i0 = __builtin_nontemporal_load(&csr_src[e]);
    float w0 = sw[i0];
    unsigned short r0 = col[(size_t)i0 * 64];
    a0 = fmaf((float)(signed char)(r0 & 0xff), w0, a0);
    a1 = fmaf((float)(signed char)(r0 >> 8), w0, a1);
  }
  a0 *= d; a1 *= d;
  out[(size_t)node * 64 + lane] = f2bf(a0) | ((unsigned)f2bf(a1) << 16);
}

// ---------------------------------------------------------------------------
// MFMA GEMM: C[M,ldc](bf16) = A[M,K](bf16) @ B[Npad,K]^T (+bias)(+relu)
// ---------------------------------------------------------------------------
__global__ __launch_bounds__(256) void k_gemm_mfma(const unsigned short* __restrict__ A,
                                                   int lda,
                                                   const unsigned short* __restrict__ B,
                                                   const float* __restrict__ bias,
                                                   unsigned short* __restrict__ C, int ldc,
                                                   int M, int K, int relu) {
  __shared__ alignas(16) unsigned short As[128][40];
  __shared__ alignas(16) unsigned short Bs[128][40];
  int tid = threadIdx.x;
  int lane = tid & 63, wv = tid >> 6;
  int wy = wv >> 1, wx = wv & 1;
  int row0 = blockIdx.x * 128, col0 = blockIdx.y * 128;

  f32x4 acc[4][4];
#pragma unroll
  for (int i = 0; i < 4; i++)
#pragma unroll
    for (int j = 0; j < 4; j++) acc[i][j] = 0.f;

  int sr0 = tid >> 2;
  int sc = (tid & 3) * 8;

  for (int k0 = 0; k0 < K; k0 += 32) {
#pragma unroll
    for (int it = 0; it < 2; it++) {
      int r = sr0 + it * 64;
      int gr = row0 + r;
      short8 va = 0;
      if (gr < M) va = *(const short8*)(A + (size_t)gr * lda + k0 + sc);
      *(short8*)&As[r][sc] = va;
      short8 vb = *(const short8*)(B + (size_t)(col0 + r) * K + k0 + sc);
      *(short8*)&Bs[r][sc] = vb;
    }
    __syncthreads();

    int ar = wy * 64 + (lane & 15);
    int br = wx * 64 + (lane & 15);
    int kk = (lane >> 4) * 8;
    short8 a[4], b[4];
#pragma unroll
    for (int mi = 0; mi < 4; mi++) a[mi] = *(const short8*)&As[ar + mi * 16][kk];
#pragma unroll
    for (int ni = 0; ni < 4; ni++) b[ni] = *(const short8*)&Bs[br + ni * 16][kk];
#pragma unroll
    for (int mi = 0; mi < 4; mi++)
#pragma unroll
      for (int ni = 0; ni < 4; ni++)
        acc[mi][ni] = __builtin_amdgcn_mfma_f32_16x16x32_bf16(a[mi], b[ni], acc[mi][ni], 0, 0, 0);
    __syncthreads();
  }

  int mbase = row0 + wy * 64;
  int nbase = col0 + wx * 64;
#pragma unroll
  for (int ni = 0; ni < 4; ni++) {
    int gc = nbase + ni * 16 + (lane & 15);
    if (gc >= ldc) continue;
    float bz = bias ? bias[gc] : 0.f;
#pragma unroll
    for (int mi = 0; mi < 4; mi++) {
      f32x4 v = acc[mi][ni];
#pragma unroll
      for (int r = 0; r < 4; r++) {
        int gr = mbase + mi * 16 + (lane >> 4) * 4 + r;
        if (gr < M) {
          float o = v[r] + bz;
          if (relu) o = fmaxf(o, 0.f);
          C[(size_t)gr * ldc + gc] = f2bf(o);
        }
      }
    }
  }
}

// ---------------------------------------------------------------------------
// layer-3: gather-agg over compact bf16 logits [N][64] + bias + log_softmax
// ---------------------------------------------------------------------------
__global__ __launch_bounds__(256) void k_agg40_lsm(const unsigned* __restrict__ in,  // [N][32]
                                                   float* __restrict__ out,
                                                   const float* __restrict__ dinv,
                                                   const int* __restrict__ row_start,
                                                   const int* __restrict__ csr_src,
                                                   const float* __restrict__ bias) {
  int node = (blockIdx.x << 2) + (threadIdx.x >> 6);
  int lane = threadIdx.x & 63;
  if (node >= N_NODES) return;
  bool act = lane < 20;
  int cl = act ? lane : 0;
  const unsigned* base = in + cl;
  float d = dinv[node];
  unsigned u0 = base[(size_t)node * 32];
  float a0 = bflo(u0) * d, a1 = bfhi(u0) * d;
  int e = row_start[node], e1 = row_start[node + 1];
  for (; e + 4 <= e1; e += 4) {
    int i0 = __builtin_nontemporal_load(&csr_src[e]);
    int i1 = __builtin_nontemporal_load(&csr_src[e + 1]);
    int i2 = __builtin_nontemporal_load(&csr_src[e + 2]);
    int i3 = __builtin_nontemporal_load(&csr_src[e + 3]);
    float w0 = dinv[i0], w1 = dinv[i1], w2 = dinv[i2], w3 = dinv[i3];
    unsigned r0 = base[(size_t)i0 * 32], r1 = base[(size_t)i1 * 32];
    unsigned r2 = base[(size_t)i2 * 32], r3 = base[(size_t)i3 * 32];
    a0 = fmaf(bflo(r0), w0, a0); a1 = fmaf(bfhi(r0), w0, a1);
    a0 = fmaf(bflo(r1), w1, a0); a1 = fmaf(bfhi(r1), w1, a1);
    a0 = fmaf(bflo(r2), w2, a0); a1 = fmaf(bfhi(r2), w2, a1);
    a0 = fmaf(bflo(r3), w3, a0); a1 = fmaf(bfhi(r3), w3, a1);
  }
  for (; e < e1; e++) {
    int i0 = __builtin_nontemporal_load(&csr_src[e]);
    float w0 = dinv[i0];
    unsigned r0 = base[(size_t)i0 * 32];
    a0 = fmaf(bflo(r0), w0, a0); a1 = fmaf(bfhi(r0), w0, a1);
  }
  float v0 = act ? a0 * d + bias[2 * lane] : -INFINITY;
  float v1 = act ? a1 * d + bias[2 * lane + 1] : -INFINITY;
  float m = fmaxf(v0, v1);
  for (int off = 32; off; off >>= 1) m = fmaxf(m, __shfl_down(m, off));
  m = __shfl(m, 0);
  float s = act ? expf(v0 - m) + expf(v1 - m) : 0.f;
  for (int off = 32; off; off >>= 1) s += __shfl_down(s, off);
  s = __shfl(s, 0);
  float lse = m + logf(s);
  if (act) {
    out[(size_t)node * N_CLS + 2 * lane] = v0 - lse;
    out[(size_t)node * N_CLS + 2 * lane + 1] = v1 - lse;
  }
}

// ---------------------------------------------------------------------------
extern "C" void kernel_launch(void* const* d_in, const int* in_sizes, int n_in,
                              void* d_out, int out_size, void* d_ws, size_t ws_size,
                              hipStream_t stream) {
  const float* x  = (const float*)d_in[0];
  const void*  ei = d_in[1];
  const float* W1 = (const float*)d_in[2];
  const float* b1 = (const float*)d_in[3];
  const float* W2 = (const float*)d_in[4];
  const float* b2 = (const float*)d_in[5];
  const float* W3 = (const float*)d_in[6];
  const float* b3 = (const float*)d_in[7];
  float* out = (float*)d_out;

  char* w = (char*)d_ws;
  auto alloc = [&](size_t bytes) {
    char* p = w;
    w += (bytes + 255) & ~(size_t)255;
    return p;
  };
  int*   flag          = (int*)alloc(64);
  int*   hist          = (int*)alloc((size_t)NBKT * 4);
  int*   bucket_start  = (int*)alloc((size_t)(NBKT + 1) * 4);
  int*   bucket_cursor = (int*)alloc((size_t)NBKT * 4);
  uint2* bpairs        = (uint2*)alloc((size_t)N_EDGES * 8);
  int*   csr_src       = (int*)alloc((size_t)N_EDGES * 4);
  int*   row_start     = (int*)alloc(((size_t)N_NODES + 1) * 4);
  float* dinv          = (float*)alloc((size_t)N_NODES * 4);
  float* sw_x          = (float*)alloc((size_t)N_NODES * 4);
  float* sw_h          = (float*)alloc((size_t)N_NODES * 4);
  unsigned short* Wt1  = (unsigned short*)alloc((size_t)HID * IN_DIM * 2);
  unsigned short* Wt2  = (unsigned short*)alloc((size_t)HID * HID * 2);
  unsigned short* Wt3  = (unsigned short*)alloc((size_t)128 * HID * 2);
  unsigned short* xq   = (unsigned short*)alloc((size_t)N_NODES * 64 * 2);  // int8 x
  unsigned*       hq   = (unsigned*)alloc((size_t)N_NODES * 64 * 4);        // uint8 h1
  char* R0 = alloc((size_t)N_NODES * HID * 2);  // 51.2 MB
  char* R1 = alloc((size_t)N_NODES * HID * 2);  // 51.2 MB

  unsigned*       aggX  = (unsigned*)R0;        // [N][64] uints = [N,128] bf16
  unsigned short* h1    = (unsigned short*)R1;  // [N,256] bf16
  uint2*          aggH1 = (uint2*)R0;           // [N][64] uint2 = [N,256] bf16 (over aggX)
  unsigned short* h2    = (unsigned short*)R1;  // [N,256] bf16 (over h1; h1 dead post-quant)
  unsigned short* C3    = (unsigned short*)R0;  // [N,64] bf16 (over aggH1)

  const int nb_w1 = (N_NODES + 3) / 4;          // 25000
  const int gm    = (N_NODES + 127) / 128;      // 782

  // CSR build
  k_pre0<<<1, 512, 0, stream>>>((const unsigned int*)ei, flag, hist);
  k_hist<<<NPB, 256, 0, stream>>>(ei, flag, hist);
  k_bscan<<<1, 512, 0, stream>>>(hist, bucket_start, bucket_cursor);
  k_part<<<NPB, 256, 0, stream>>>(ei, flag, bucket_cursor, bpairs);
  k_bsort<<<NBKT, 256, 0, stream>>>(bpairs, bucket_start, row_start, dinv, csr_src);

  // weight prep + x quantization (needs dinv)
  k_wprep<<<512, 256, 0, stream>>>(W1, W2, W3, Wt1, Wt2, Wt3);
  k_qx<<<nb_w1, 256, 0, stream>>>(x, dinv, xq, sw_x);

  // layer 1: agg_int8(x) @ W1 + b1, relu
  k_agg128i<<<nb_w1, 256, 0, stream>>>(xq, aggX, dinv, sw_x, row_start, csr_src);
  k_gemm_mfma<<<dim3(gm, 2), 256, 0, stream>>>((const unsigned short*)aggX, IN_DIM, Wt1, b1,
                                               h1, HID, N_NODES, IN_DIM, 1);
  // quantize h1, layer 2: agg_int8(h1) @ W2 + b2, relu
  k_qh<<<nb_w1, 256, 0, stream>>>((const uint2*)h1, dinv, hq, sw_h);
  k_agg256i<<<nb_w1, 256, 0, stream>>>(hq, aggH1, dinv, sw_h, row_start, csr_src);
  k_gemm_mfma<<<dim3(gm, 2), 256, 0, stream>>>((const unsigned short*)aggH1, HID, Wt2, b2,
                                               h2, HID, N_NODES, HID, 1);
  // layer 3: agg(h2 @ W3) + b3, log_softmax (bf16 logits path)
  k_gemm_mfma<<<dim3(gm, 1), 256, 0, stream>>>(h2, HID, Wt3, nullptr,
                                               C3, 64, N_NODES, HID, 0);
  k_agg40_lsm<<<nb_w1, 256, 0, stream>>>((const unsigned*)C3, out, dinv, row_start,
                                         csr_src, b3);
}

// Round 9
// 562.265 us; speedup vs baseline: 1.0945x; 1.0945x over previous
//
#include <hip/hip_runtime.h>
#include <stdint.h>
#include <math.h>

#define N_NODES 100000
#define N_EDGES 1600000
#define IN_DIM 128
#define HID 256
#define N_CLS 40
#define NBKT 391                 // buckets of 256 dst nodes
#define NPB 391                  // edge partition blocks: ceil(1.6M/4096)

typedef __attribute__((ext_vector_type(8))) short short8;
typedef __attribute__((ext_vector_type(4))) float f32x4;

__device__ __forceinline__ unsigned short f2bf(float f) {
  unsigned b = __float_as_uint(f);
  b += 0x7fffu + ((b >> 16) & 1u);   // round-to-nearest-even
  return (unsigned short)(b >> 16);
}
__device__ __forceinline__ float bflo(unsigned u) { return __uint_as_float(u << 16); }
__device__ __forceinline__ float bfhi(unsigned u) { return __uint_as_float(u & 0xffff0000u); }

__device__ __forceinline__ int load_idx(const void* eidx, int flag, size_t pos) {
  return flag ? (int)((const long long*)eidx)[pos] : ((const int*)eidx)[pos];
}

// ---------------------------------------------------------------------------
// detect edge_index dtype + zero bucket histogram. One block.
// ---------------------------------------------------------------------------
__global__ __launch_bounds__(512) void k_pre0(const unsigned int* __restrict__ ew,
                                              int* __restrict__ flag,
                                              int* __restrict__ hist) {
  int t = threadIdx.x;
  for (int k = t; k < NBKT; k += 512) hist[k] = 0;
  __shared__ unsigned int sh[512];
  unsigned int v = 0;
  for (int k = t; k < 4096; k += 512) v |= ew[2 * k + 1];
  sh[t] = v;
  __syncthreads();
  for (int s = 256; s > 0; s >>= 1) {
    if (t < s) sh[t] |= sh[t + s];
    __syncthreads();
  }
  if (t == 0) flag[0] = (sh[0] == 0u) ? 1 : 0;
}

// bucket histogram over dst (bucket = dst>>8), LDS-aggregated
__global__ __launch_bounds__(256) void k_hist(const void* __restrict__ eidx,
                                              const int* __restrict__ flagp,
                                              int* __restrict__ hist) {
  __shared__ int lh[NBKT];
  int t = threadIdx.x;
  for (int k = t; k < NBKT; k += 256) lh[k] = 0;
  __syncthreads();
  int flag = flagp[0];
  int base = blockIdx.x * 4096;
#pragma unroll
  for (int j = 0; j < 16; j++) {
    int e = base + j * 256 + t;
    if (e < N_EDGES) {
      int d = load_idx(eidx, flag, (size_t)N_EDGES + e);
      atomicAdd(&lh[d >> 8], 1);
    }
  }
  __syncthreads();
  for (int k = t; k < NBKT; k += 256) {
    int c = lh[k];
    if (c) atomicAdd(&hist[k], c);
  }
}

// exclusive scan of buckets -> bucket_start[392], init bucket_cursor
__global__ __launch_bounds__(512) void k_bscan(const int* __restrict__ hist,
                                               int* __restrict__ bucket_start,
                                               int* __restrict__ bucket_cursor) {
  __shared__ int sh[512];
  int t = threadIdx.x;
  int v = (t < NBKT) ? hist[t] : 0;
  sh[t] = v;
  __syncthreads();
  for (int off = 1; off < 512; off <<= 1) {
    int u = (t >= off) ? sh[t - off] : 0;
    __syncthreads();
    sh[t] += u;
    __syncthreads();
  }
  if (t < NBKT) {
    bucket_start[t + 1] = sh[t];
    bucket_cursor[t] = sh[t] - v;
  }
  if (t == 0) bucket_start[0] = 0;
}

// partition edges into bucket-segmented (src,dst) pairs
__global__ __launch_bounds__(256) void k_part(const void* __restrict__ eidx,
                                              const int* __restrict__ flagp,
                                              int* __restrict__ bucket_cursor,
                                              uint2* __restrict__ bpairs) {
  __shared__ int lcur[NBKT];
  int t = threadIdx.x;
  for (int k = t; k < NBKT; k += 256) lcur[k] = 0;
  __syncthreads();
  int flag = flagp[0];
  int base = blockIdx.x * 4096;
#pragma unroll
  for (int j = 0; j < 16; j++) {
    int e = base + j * 256 + t;
    if (e < N_EDGES) {
      int d = load_idx(eidx, flag, (size_t)N_EDGES + e);
      atomicAdd(&lcur[d >> 8], 1);
    }
  }
  __syncthreads();
  for (int k = t; k < NBKT; k += 256) {
    int c = lcur[k];
    int g = c ? atomicAdd(&bucket_cursor[k], c) : 0;
    lcur[k] = g;
  }
  __syncthreads();
#pragma unroll
  for (int j = 0; j < 16; j++) {
    int e = base + j * 256 + t;
    if (e < N_EDGES) {
      int s = load_idx(eidx, flag, e);
      int d = load_idx(eidx, flag, (size_t)N_EDGES + e);
      int p = atomicAdd(&lcur[d >> 8], 1);
      bpairs[p] = make_uint2((unsigned)s, (unsigned)d);
    }
  }
}

// per-bucket finalize: local deg -> row_start + dinv + csr placement
__global__ __launch_bounds__(256) void k_bsort(const uint2* __restrict__ bpairs,
                                               const int* __restrict__ bucket_start,
                                               int* __restrict__ row_start,
                                               float* __restrict__ dinv,
                                               int* __restrict__ csr_src) {
  __shared__ int ldeg[256], lsum[256], lcur[256];
  int b = blockIdx.x, t = threadIdx.x;
  int d0 = b << 8;
  int nd = min(256, N_NODES - d0);
  int base = bucket_start[b];
  int n = bucket_start[b + 1] - base;
  ldeg[t] = 0;
  __syncthreads();
  for (int i = t; i < n; i += 256) {
    uint2 p = bpairs[base + i];
    atomicAdd(&ldeg[p.y - d0], 1);
  }
  __syncthreads();
  lsum[t] = ldeg[t];
  __syncthreads();
  for (int off = 1; off < 256; off <<= 1) {
    int v = (t >= off) ? lsum[t - off] : 0;
    __syncthreads();
    lsum[t] += v;
    __syncthreads();
  }
  int excl = lsum[t] - ldeg[t];
  if (t < nd) {
    row_start[d0 + t] = base + excl;
    dinv[d0 + t] = rsqrtf((float)(ldeg[t] + 1));
  }
  lcur[t] = base + excl;
  __syncthreads();
  for (int i = t; i < n; i += 256) {
    uint2 p = bpairs[base + i];
    int pos = atomicAdd(&lcur[p.y - d0], 1);
    csr_src[pos] = (int)p.x;
  }
  if (b == 0 && t == 0) row_start[N_NODES] = N_EDGES;
}

// ---------------------------------------------------------------------------
// weight prep: transpose + bf16
// ---------------------------------------------------------------------------
__global__ __launch_bounds__(256) void k_wprep(const float* __restrict__ W1,
                                               const float* __restrict__ W2,
                                               const float* __restrict__ W3,
                                               unsigned short* __restrict__ T1,
                                               unsigned short* __restrict__ T2,
                                               unsigned short* __restrict__ T3) {
  int idx = blockIdx.x * 256 + threadIdx.x;
  if (idx < 32768) {
    int n = idx >> 7, k = idx & 127;
    T1[idx] = f2bf(W1[(size_t)k * HID + n]);
  } else if (idx < 98304) {
    int j = idx - 32768;
    int n = j >> 8, k = j & 255;
    T2[j] = f2bf(W2[(size_t)k * HID + n]);
  } else if (idx < 131072) {
    int j = idx - 98304;
    int n = j >> 8, k = j & 255;
    T3[j] = f2bf((n < N_CLS) ? W3[(size_t)k * N_CLS + n] : 0.f);
  }
}

// ---------------------------------------------------------------------------
// quantize x: fp32 [N][128] -> signed int8 [N][64] ushort-packed, per-row scale
// folded into sw_x[i] = dinv[i] * scale_i. One wave per row.
// ---------------------------------------------------------------------------
__global__ __launch_bounds__(256) void k_qx(const float* __restrict__ x,
                                            const float* __restrict__ dinv,
                                            unsigned short* __restrict__ xq,
                                            float* __restrict__ sw_x) {
  int node = (blockIdx.x << 2) + (threadIdx.x >> 6);
  int lane = threadIdx.x & 63;
  if (node >= N_NODES) return;
  float2 v = ((const float2*)x)[(size_t)node * 64 + lane];
  float m = fmaxf(fabsf(v.x), fabsf(v.y));
  for (int off = 32; off; off >>= 1) m = fmaxf(m, __shfl_down(m, off));
  m = __shfl(m, 0);
  float inv = (m > 0.f) ? 127.f / m : 0.f;
  int q0 = __float2int_rn(v.x * inv);
  int q1 = __float2int_rn(v.y * inv);
  xq[(size_t)node * 64 + lane] = (unsigned short)((q0 & 0xff) | ((q1 & 0xff) << 8));
  if (lane == 0) sw_x[node] = dinv[node] * ((m > 0.f) ? m / 127.f : 0.f);
}

// ---------------------------------------------------------------------------
// quantize h1: bf16 [N][256] (>=0 after relu) -> uint8 [N][64] uint-packed,
// per-row scale folded into sw_h[i] = dinv[i] * scale_i. One wave per row.
// ---------------------------------------------------------------------------
__global__ __launch_bounds__(256) void k_qh(const uint2* __restrict__ h1,  // [N][64]
                                            const float* __restrict__ dinv,
                                            unsigned* __restrict__ hq,
                                            float* __restrict__ sw_h) {
  int node = (blockIdx.x << 2) + (threadIdx.x >> 6);
  int lane = threadIdx.x & 63;
  if (node >= N_NODES) return;
  uint2 v = h1[(size_t)node * 64 + lane];
  float b0 = bflo(v.x), b1 = bfhi(v.x), b2 = bflo(v.y), b3 = bfhi(v.y);
  float m = fmaxf(fmaxf(b0, b1), fmaxf(b2, b3));
  for (int off = 32; off; off >>= 1) m = fmaxf(m, __shfl_down(m, off));
  m = __shfl(m, 0);
  float inv = (m > 0.f) ? 255.f / m : 0.f;
  unsigned q0 = (unsigned)__float2int_rn(b0 * inv);
  unsigned q1 = (unsigned)__float2int_rn(b1 * inv);
  unsigned q2 = (unsigned)__float2int_rn(b2 * inv);
  unsigned q3 = (unsigned)__float2int_rn(b3 * inv);
  hq[(size_t)node * 64 + lane] = q0 | (q1 << 8) | (q2 << 16) | (q3 << 24);
  if (lane == 0) sw_h[node] = dinv[node] * ((m > 0.f) ? m / 255.f : 0.f);
}

// ---------------------------------------------------------------------------
// int8 gather aggregation, 256-dim: 1 wave/node, 4 uint8/lane, unroll x8.
// ---------------------------------------------------------------------------
__device__ __forceinline__ void up4u(unsigned v, float w,
                                     float& a0, float& a1, float& a2, float& a3) {
  a0 = fmaf((float)(v & 0xffu), w, a0);
  a1 = fmaf((float)((v >> 8) & 0xffu), w, a1);
  a2 = fmaf((float)((v >> 16) & 0xffu), w, a2);
  a3 = fmaf((float)(v >> 24), w, a3);
}

__global__ __launch_bounds__(256) void k_agg256i(const unsigned* __restrict__ tbl,  // [N][64]
                                                 uint2* __restrict__ out,           // [N][64]
                                                 const float* __restrict__ dinv,
                                                 const float* __restrict__ sw,
                                                 const int* __restrict__ row_start,
                                                 const int* __restrict__ csr_src) {
  int node = (blockIdx.x << 2) + (threadIdx.x >> 6);
  int lane = threadIdx.x & 63;
  if (node >= N_NODES) return;
  const unsigned* col = tbl + lane;
  float d = dinv[node];
  float ws = sw[node];
  unsigned v0 = col[(size_t)node * 64];
  float a0 = 0.f, a1 = 0.f, a2 = 0.f, a3 = 0.f;
  up4u(v0, ws, a0, a1, a2, a3);
  int e = row_start[node], e1 = row_start[node + 1];
  for (; e + 8 <= e1; e += 8) {
    int i0 = csr_src[e],     i1 = csr_src[e + 1], i2 = csr_src[e + 2], i3 = csr_src[e + 3];
    int i4 = csr_src[e + 4], i5 = csr_src[e + 5], i6 = csr_src[e + 6], i7 = csr_src[e + 7];
    float w0 = sw[i0], w1 = sw[i1], w2 = sw[i2], w3 = sw[i3];
    float w4 = sw[i4], w5 = sw[i5], w6 = sw[i6], w7 = sw[i7];
    unsigned r0 = col[(size_t)i0 * 64], r1 = col[(size_t)i1 * 64];
    unsigned r2 = col[(size_t)i2 * 64], r3 = col[(size_t)i3 * 64];
    unsigned r4 = col[(size_t)i4 * 64], r5 = col[(size_t)i5 * 64];
    unsigned r6 = col[(size_t)i6 * 64], r7 = col[(size_t)i7 * 64];
    up4u(r0, w0, a0, a1, a2, a3);
    up4u(r1, w1, a0, a1, a2, a3);
    up4u(r2, w2, a0, a1, a2, a3);
    up4u(r3, w3, a0, a1, a2, a3);
    up4u(r4, w4, a0, a1, a2, a3);
    up4u(r5, w5, a0, a1, a2, a3);
    up4u(r6, w6, a0, a1, a2, a3);
    up4u(r7, w7, a0, a1, a2, a3);
  }
  for (; e < e1; e++) {
    int i0 = csr_src[e];
    float w0 = sw[i0];
    unsigned r0 = col[(size_t)i0 * 64];
    up4u(r0, w0, a0, a1, a2, a3);
  }
  a0 *= d; a1 *= d; a2 *= d; a3 *= d;
  uint2 o;
  o.x = f2bf(a0) | ((unsigned)f2bf(a1) << 16);
  o.y = f2bf(a2) | ((unsigned)f2bf(a3) << 16);
  out[(size_t)node * 64 + lane] = o;
}

// int8 gather aggregation, 128-dim: 2 int8/lane (ushort), unroll x8.
__global__ __launch_bounds__(256) void k_agg128i(const unsigned short* __restrict__ tbl,
                                                 unsigned* __restrict__ out,  // [N][64]
                                                 const float* __restrict__ dinv,
                                                 const float* __restrict__ sw,
                                                 const int* __restrict__ row_start,
                                                 const int* __restrict__ csr_src) {
  int node = (blockIdx.x << 2) + (threadIdx.x >> 6);
  int lane = threadIdx.x & 63;
  if (node >= N_NODES) return;
  const unsigned short* col = tbl + lane;
  float d = dinv[node];
  float ws = sw[node];
  unsigned short v0 = col[(size_t)node * 64];
  float a0 = (float)(signed char)(v0 & 0xff) * ws;
  float a1 = (float)(signed char)(v0 >> 8) * ws;
  int e = row_start[node], e1 = row_start[node + 1];
  for (; e + 8 <= e1; e += 8) {
    int i0 = csr_src[e],     i1 = csr_src[e + 1], i2 = csr_src[e + 2], i3 = csr_src[e + 3];
    int i4 = csr_src[e + 4], i5 = csr_src[e + 5], i6 = csr_src[e + 6], i7 = csr_src[e + 7];
    float w0 = sw[i0], w1 = sw[i1], w2 = sw[i2], w3 = sw[i3];
    float w4 = sw[i4], w5 = sw[i5], w6 = sw[i6], w7 = sw[i7];
    unsigned short r0 = col[(size_t)i0 * 64], r1 = col[(size_t)i1 * 64];
    unsigned short r2 = col[(size_t)i2 * 64], r3 = col[(size_t)i3 * 64];
    unsigned short r4 = col[(size_t)i4 * 64], r5 = col[(size_t)i5 * 64];
    unsigned short r6 = col[(size_t)i6 * 64], r7 = col[(size_t)i7 * 64];
    a0 = fmaf((float)(signed char)(r0 & 0xff), w0, a0);
    a1 = fmaf((float)(signed char)(r0 >> 8), w0, a1);
    a0 = fmaf((float)(signed char)(r1 & 0xff), w1, a0);
    a1 = fmaf((float)(signed char)(r1 >> 8), w1, a1);
    a0 = fmaf((float)(signed char)(r2 & 0xff), w2, a0);
    a1 = fmaf((float)(signed char)(r2 >> 8), w2, a1);
    a0 = fmaf((float)(signed char)(r3 & 0xff), w3, a0);
    a1 = fmaf((float)(signed char)(r3 >> 8), w3, a1);
    a0 = fmaf((float)(signed char)(r4 & 0xff), w4, a0);
    a1 = fmaf((float)(signed char)(r4 >> 8), w4, a1);
    a0 = fmaf((float)(signed char)(r5 & 0xff), w5, a0);
    a1 = fmaf((float)(signed char)(r5 >> 8), w5, a1);
    a0 = fmaf((float)(signed char)(r6 & 0xff), w6, a0);
    a1 = fmaf((float)(signed char)(r6 >> 8), w6, a1);
    a0 = fmaf((float)(signed char)(r7 & 0xff), w7, a0);
    a1 = fmaf((float)(signed char)(r7 >> 8), w7, a1);
  }
  for (; e < e1; e++) {
    int i0 = csr_src[e];
    float w0 = sw[i0];
    unsigned short r0 = col[(size_t)i0 * 64];
    a0 = fmaf((float)(signed char)(r0 & 0xff), w0, a0);
    a1 = fmaf((float)(signed char)(r0 >> 8), w0, a1);
  }
  a0 *= d; a1 *= d;
  out[(size_t)node * 64 + lane] = f2bf(a0) | ((unsigned)f2bf(a1) << 16);
}

// ---------------------------------------------------------------------------
// MFMA GEMM: C[M,ldc](bf16) = A[M,K](bf16) @ B[Npad,K]^T (+bias)(+relu)
// ---------------------------------------------------------------------------
__global__ __launch_bounds__(256) void k_gemm_mfma(const unsigned short* __restrict__ A,
                                                   int lda,
                                                   const unsigned short* __restrict__ B,
                                                   const float* __restrict__ bias,
                                                   unsigned short* __restrict__ C, int ldc,
                                                   int M, int K, int relu) {
  __shared__ alignas(16) unsigned short As[128][40];
  __shared__ alignas(16) unsigned short Bs[128][40];
  int tid = threadIdx.x;
  int lane = tid & 63, wv = tid >> 6;
  int wy = wv >> 1, wx = wv & 1;
  int row0 = blockIdx.x * 128, col0 = blockIdx.y * 128;

  f32x4 acc[4][4];
#pragma unroll
  for (int i = 0; i < 4; i++)
#pragma unroll
    for (int j = 0; j < 4; j++) acc[i][j] = 0.f;

  int sr0 = tid >> 2;
  int sc = (tid & 3) * 8;

  for (int k0 = 0; k0 < K; k0 += 32) {
#pragma unroll
    for (int it = 0; it < 2; it++) {
      int r = sr0 + it * 64;
      int gr = row0 + r;
      short8 va = 0;
      if (gr < M) va = *(const short8*)(A + (size_t)gr * lda + k0 + sc);
      *(short8*)&As[r][sc] = va;
      short8 vb = *(const short8*)(B + (size_t)(col0 + r) * K + k0 + sc);
      *(short8*)&Bs[r][sc] = vb;
    }
    __syncthreads();

    int ar = wy * 64 + (lane & 15);
    int br = wx * 64 + (lane & 15);
    int kk = (lane >> 4) * 8;
    short8 a[4], b[4];
#pragma unroll
    for (int mi = 0; mi < 4; mi++) a[mi] = *(const short8*)&As[ar + mi * 16][kk];
#pragma unroll
    for (int ni = 0; ni < 4; ni++) b[ni] = *(const short8*)&Bs[br + ni * 16][kk];
#pragma unroll
    for (int mi = 0; mi < 4; mi++)
#pragma unroll
      for (int ni = 0; ni < 4; ni++)
        acc[mi][ni] = __builtin_amdgcn_mfma_f32_16x16x32_bf16(a[mi], b[ni], acc[mi][ni], 0, 0, 0);
    __syncthreads();
  }

  int mbase = row0 + wy * 64;
  int nbase = col0 + wx * 64;
#pragma unroll
  for (int ni = 0; ni < 4; ni++) {
    int gc = nbase + ni * 16 + (lane & 15);
    if (gc >= ldc) continue;
    float bz = bias ? bias[gc] : 0.f;
#pragma unroll
    for (int mi = 0; mi < 4; mi++) {
      f32x4 v = acc[mi][ni];
#pragma unroll
      for (int r = 0; r < 4; r++) {
        int gr = mbase + mi * 16 + (lane >> 4) * 4 + r;
        if (gr < M) {
          float o = v[r] + bz;
          if (relu) o = fmaxf(o, 0.f);
          C[(size_t)gr * ldc + gc] = f2bf(o);
        }
      }
    }
  }
}

// ---------------------------------------------------------------------------
// layer-3: gather-agg over compact bf16 logits [N][64] + bias + log_softmax.
// 3-way lane-group parallelism: lane groups [0,20)/[20,40)/[40,60) each take a
// different edge -> 3 concurrent 80B gathers; unroll x2 -> 6 in flight.
// ---------------------------------------------------------------------------
__global__ __launch_bounds__(256) void k_agg40_lsm(const unsigned* __restrict__ in,  // [N][32]
                                                   float* __restrict__ out,
                                                   const float* __restrict__ dinv,
                                                   const int* __restrict__ row_start,
                                                   const int* __restrict__ csr_src,
                                                   const float* __restrict__ bias) {
  int node = (blockIdx.x << 2) + (threadIdx.x >> 6);
  int lane = threadIdx.x & 63;
  if (node >= N_NODES) return;
  // lane -> (group g in 0..2, class-pair c in 0..19); lanes 60-63 idle
  int g = (lane >= 40) ? 2 : (lane >= 20 ? 1 : 0);
  int c = lane - g * 20;
  bool act3 = lane < 60;
  const unsigned* base = in + c;
  float d = dinv[node];
  // self term counted only in group 0
  float ws = (g == 0 && act3) ? d : 0.f;
  unsigned u0 = base[(size_t)node * 32];
  float a0 = bflo(u0) * ws, a1 = bfhi(u0) * ws;
  int e0 = row_start[node], e1 = row_start[node + 1];
  int eb = e0;
  for (; eb + 6 <= e1; eb += 6) {
    int ea = eb + g, ebx = eb + 3 + g;
    int ia = csr_src[ea];
    int ib = csr_src[ebx];
    float wa = act3 ? dinv[ia] : 0.f;
    float wb = act3 ? dinv[ib] : 0.f;
    unsigned ra = base[(size_t)ia * 32];
    unsigned rb = base[(size_t)ib * 32];
    a0 = fmaf(bflo(ra), wa, a0); a1 = fmaf(bfhi(ra), wa, a1);
    a0 = fmaf(bflo(rb), wb, a0); a1 = fmaf(bfhi(rb), wb, a1);
  }
  for (; eb < e1; eb += 3) {
    int ea = eb + g;
    bool v = act3 && (ea < e1);
    int ia = v ? csr_src[ea] : 0;
    float wa = v ? dinv[ia] : 0.f;
    unsigned ra = base[(size_t)ia * 32];
    a0 = fmaf(bflo(ra), wa, a0); a1 = fmaf(bfhi(ra), wa, a1);
  }
  // cross-group reduction: class c lives in lanes c, c+20, c+40
  a0 += __shfl(a0, c + 20) + __shfl(a0, c + 40);
  a1 += __shfl(a1, c + 20) + __shfl(a1, c + 40);
  bool act = lane < 20;
  float v0 = act ? a0 * d + bias[2 * lane] : -INFINITY;
  float v1 = act ? a1 * d + bias[2 * lane + 1] : -INFINITY;
  float m = fmaxf(v0, v1);
  for (int off = 32; off; off >>= 1) m = fmaxf(m, __shfl_down(m, off));
  m = __shfl(m, 0);
  float s = act ? expf(v0 - m) + expf(v1 - m) : 0.f;
  for (int off = 32; off; off >>= 1) s += __shfl_down(s, off);
  s = __shfl(s, 0);
  float lse = m + logf(s);
  if (act) {
    out[(size_t)node * N_CLS + 2 * lane] = v0 - lse;
    out[(size_t)node * N_CLS + 2 * lane + 1] = v1 - lse;
  }
}

// ---------------------------------------------------------------------------
extern "C" void kernel_launch(void* const* d_in, const int* in_sizes, int n_in,
                              void* d_out, int out_size, void* d_ws, size_t ws_size,
                              hipStream_t stream) {
  const float* x  = (const float*)d_in[0];
  const void*  ei = d_in[1];
  const float* W1 = (const float*)d_in[2];
  const float* b1 = (const float*)d_in[3];
  const float* W2 = (const float*)d_in[4];
  const float* b2 = (const float*)d_in[5];
  const float* W3 = (const float*)d_in[6];
  const float* b3 = (const float*)d_in[7];
  float* out = (float*)d_out;

  char* w = (char*)d_ws;
  auto alloc = [&](size_t bytes) {
    char* p = w;
    w += (bytes + 255) & ~(size_t)255;
    return p;
  };
  int*   flag          = (int*)alloc(64);
  int*   hist          = (int*)alloc((size_t)NBKT * 4);
  int*   bucket_start  = (int*)alloc((size_t)(NBKT + 1) * 4);
  int*   bucket_cursor = (int*)alloc((size_t)NBKT * 4);
  uint2* bpairs        = (uint2*)alloc((size_t)N_EDGES * 8);
  int*   csr_src       = (int*)alloc((size_t)N_EDGES * 4);
  int*   row_start     = (int*)alloc(((size_t)N_NODES + 1) * 4);
  float* dinv          = (float*)alloc((size_t)N_NODES * 4);
  float* sw_x          = (float*)alloc((size_t)N_NODES * 4);
  float* sw_h          = (float*)alloc((size_t)N_NODES * 4);
  unsigned short* Wt1  = (unsigned short*)alloc((size_t)HID * IN_DIM * 2);
  unsigned short* Wt2  = (unsigned short*)alloc((size_t)HID * HID * 2);
  unsigned short* Wt3  = (unsigned short*)alloc((size_t)128 * HID * 2);
  unsigned short* xq   = (unsigned short*)alloc((size_t)N_NODES * 64 * 2);  // int8 x
  unsigned*       hq   = (unsigned*)alloc((size_t)N_NODES * 64 * 4);        // uint8 h1
  char* R0 = alloc((size_t)N_NODES * HID * 2);  // 51.2 MB
  char* R1 = alloc((size_t)N_NODES * HID * 2);  // 51.2 MB

  unsigned*       aggX  = (unsigned*)R0;        // [N][64] uints = [N,128] bf16
  unsigned short* h1    = (unsigned short*)R1;  // [N,256] bf16
  uint2*          aggH1 = (uint2*)R0;           // [N][64] uint2 = [N,256] bf16 (over aggX)
  unsigned short* h2    = (unsigned short*)R1;  // [N,256] bf16 (over h1; h1 dead post-quant)
  unsigned short* C3    = (unsigned short*)R0;  // [N,64] bf16 (over aggH1)

  const int nb_w1 = (N_NODES + 3) / 4;          // 25000
  const int gm    = (N_NODES + 127) / 128;      // 782

  // CSR build
  k_pre0<<<1, 512, 0, stream>>>((const unsigned int*)ei, flag, hist);
  k_hist<<<NPB, 256, 0, stream>>>(ei, flag, hist);
  k_bscan<<<1, 512, 0, stream>>>(hist, bucket_start, bucket_cursor);
  k_part<<<NPB, 256, 0, stream>>>(ei, flag, bucket_cursor, bpairs);
  k_bsort<<<NBKT, 256, 0, stream>>>(bpairs, bucket_start, row_start, dinv, csr_src);

  // weight prep + x quantization (needs dinv)
  k_wprep<<<512, 256, 0, stream>>>(W1, W2, W3, Wt1, Wt2, Wt3);
  k_qx<<<nb_w1, 256, 0, stream>>>(x, dinv, xq, sw_x);

  // layer 1: agg_int8(x) @ W1 + b1, relu
  k_agg128i<<<nb_w1, 256, 0, stream>>>(xq, aggX, dinv, sw_x, row_start, csr_src);
  k_gemm_mfma<<<dim3(gm, 2), 256, 0, stream>>>((const unsigned short*)aggX, IN_DIM, Wt1, b1,
                                               h1, HID, N_NODES, IN_DIM, 1);
  // quantize h1, layer 2: agg_int8(h1) @ W2 + b2, relu
  k_qh<<<nb_w1, 256, 0, stream>>>((const uint2*)h1, dinv, hq, sw_h);
  k_agg256i<<<nb_w1, 256, 0, stream>>>(hq, aggH1, dinv, sw_h, row_start, csr_src);
  k_gemm_mfma<<<dim3(gm, 2), 256, 0, stream>>>((const unsigned short*)aggH1, HID, Wt2, b2,
                                               h2, HID, N_NODES, HID, 1);
  // layer 3: agg(h2 @ W3) + b3, log_softmax (bf16 logits path)
  k_gemm_mfma<<<dim3(gm, 1), 256, 0, stream>>>(h2, HID, Wt3, nullptr,
                                               C3, 64, N_NODES, HID, 0);
  k_agg40_lsm<<<nb_w1, 256, 0, stream>>>((const unsigned*)C3, out, dinv, row_start,
                                         csr_src, b3);
}

// Round 10
// 526.934 us; speedup vs baseline: 1.1678x; 1.0671x over previous
//
#include <hip/hip_runtime.h>
#include <stdint.h>
#include <math.h>

#define N_NODES 100000
#define N_EDGES 1600000
#define IN_DIM 128
#define HID 256
#define N_CLS 40
#define NBKT 391                 // buckets of 256 dst nodes
#define NPB 391                  // edge partition blocks: ceil(1.6M/4096)

typedef __attribute__((ext_vector_type(8))) short short8;
typedef __attribute__((ext_vector_type(4))) float f32x4;

__device__ __forceinline__ unsigned short f2bf(float f) {
  unsigned b = __float_as_uint(f);
  b += 0x7fffu + ((b >> 16) & 1u);   // round-to-nearest-even
  return (unsigned short)(b >> 16);
}
__device__ __forceinline__ float bflo(unsigned u) { return __uint_as_float(u << 16); }
__device__ __forceinline__ float bfhi(unsigned u) { return __uint_as_float(u & 0xffff0000u); }

__device__ __forceinline__ int load_idx(const void* eidx, int flag, size_t pos) {
  return flag ? (int)((const long long*)eidx)[pos] : ((const int*)eidx)[pos];
}

// ---------------------------------------------------------------------------
// detect edge_index dtype + zero bucket histogram. One block.
// ---------------------------------------------------------------------------
__global__ __launch_bounds__(512) void k_pre0(const unsigned int* __restrict__ ew,
                                              int* __restrict__ flag,
                                              int* __restrict__ hist) {
  int t = threadIdx.x;
  for (int k = t; k < NBKT; k += 512) hist[k] = 0;
  __shared__ unsigned int sh[512];
  unsigned int v = 0;
  for (int k = t; k < 4096; k += 512) v |= ew[2 * k + 1];
  sh[t] = v;
  __syncthreads();
  for (int s = 256; s > 0; s >>= 1) {
    if (t < s) sh[t] |= sh[t + s];
    __syncthreads();
  }
  if (t == 0) flag[0] = (sh[0] == 0u) ? 1 : 0;
}

// bucket histogram over dst (bucket = dst>>8), LDS-aggregated
__global__ __launch_bounds__(256) void k_hist(const void* __restrict__ eidx,
                                              const int* __restrict__ flagp,
                                              int* __restrict__ hist) {
  __shared__ int lh[NBKT];
  int t = threadIdx.x;
  for (int k = t; k < NBKT; k += 256) lh[k] = 0;
  __syncthreads();
  int flag = flagp[0];
  int base = blockIdx.x * 4096;
#pragma unroll
  for (int j = 0; j < 16; j++) {
    int e = base + j * 256 + t;
    if (e < N_EDGES) {
      int d = load_idx(eidx, flag, (size_t)N_EDGES + e);
      atomicAdd(&lh[d >> 8], 1);
    }
  }
  __syncthreads();
  for (int k = t; k < NBKT; k += 256) {
    int c = lh[k];
    if (c) atomicAdd(&hist[k], c);
  }
}

// exclusive scan of buckets -> bucket_start[392], init bucket_cursor
__global__ __launch_bounds__(512) void k_bscan(const int* __restrict__ hist,
                                               int* __restrict__ bucket_start,
                                               int* __restrict__ bucket_cursor) {
  __shared__ int sh[512];
  int t = threadIdx.x;
  int v = (t < NBKT) ? hist[t] : 0;
  sh[t] = v;
  __syncthreads();
  for (int off = 1; off < 512; off <<= 1) {
    int u = (t >= off) ? sh[t - off] : 0;
    __syncthreads();
    sh[t] += u;
    __syncthreads();
  }
  if (t < NBKT) {
    bucket_start[t + 1] = sh[t];
    bucket_cursor[t] = sh[t] - v;
  }
  if (t == 0) bucket_start[0] = 0;
}

// partition edges into bucket-segmented (src,dst) pairs
__global__ __launch_bounds__(256) void k_part(const void* __restrict__ eidx,
                                              const int* __restrict__ flagp,
                                              int* __restrict__ bucket_cursor,
                                              uint2* __restrict__ bpairs) {
  __shared__ int lcur[NBKT];
  int t = threadIdx.x;
  for (int k = t; k < NBKT; k += 256) lcur[k] = 0;
  __syncthreads();
  int flag = flagp[0];
  int base = blockIdx.x * 4096;
#pragma unroll
  for (int j = 0; j < 16; j++) {
    int e = base + j * 256 + t;
    if (e < N_EDGES) {
      int d = load_idx(eidx, flag, (size_t)N_EDGES + e);
      atomicAdd(&lcur[d >> 8], 1);
    }
  }
  __syncthreads();
  for (int k = t; k < NBKT; k += 256) {
    int c = lcur[k];
    int g = c ? atomicAdd(&bucket_cursor[k], c) : 0;
    lcur[k] = g;
  }
  __syncthreads();
#pragma unroll
  for (int j = 0; j < 16; j++) {
    int e = base + j * 256 + t;
    if (e < N_EDGES) {
      int s = load_idx(eidx, flag, e);
      int d = load_idx(eidx, flag, (size_t)N_EDGES + e);
      int p = atomicAdd(&lcur[d >> 8], 1);
      bpairs[p] = make_uint2((unsigned)s, (unsigned)d);
    }
  }
}

// per-bucket finalize: local deg -> row_start + dinv + csr placement
__global__ __launch_bounds__(256) void k_bsort(const uint2* __restrict__ bpairs,
                                               const int* __restrict__ bucket_start,
                                               int* __restrict__ row_start,
                                               float* __restrict__ dinv,
                                               int* __restrict__ csr_src) {
  __shared__ int ldeg[256], lsum[256], lcur[256];
  int b = blockIdx.x, t = threadIdx.x;
  int d0 = b << 8;
  int nd = min(256, N_NODES - d0);
  int base = bucket_start[b];
  int n = bucket_start[b + 1] - base;
  ldeg[t] = 0;
  __syncthreads();
  for (int i = t; i < n; i += 256) {
    uint2 p = bpairs[base + i];
    atomicAdd(&ldeg[p.y - d0], 1);
  }
  __syncthreads();
  lsum[t] = ldeg[t];
  __syncthreads();
  for (int off = 1; off < 256; off <<= 1) {
    int v = (t >= off) ? lsum[t - off] : 0;
    __syncthreads();
    lsum[t] += v;
    __syncthreads();
  }
  int excl = lsum[t] - ldeg[t];
  if (t < nd) {
    row_start[d0 + t] = base + excl;
    dinv[d0 + t] = rsqrtf((float)(ldeg[t] + 1));
  }
  lcur[t] = base + excl;
  __syncthreads();
  for (int i = t; i < n; i += 256) {
    uint2 p = bpairs[base + i];
    int pos = atomicAdd(&lcur[p.y - d0], 1);
    csr_src[pos] = (int)p.x;
  }
  if (b == 0 && t == 0) row_start[N_NODES] = N_EDGES;
}

// ---------------------------------------------------------------------------
// weight prep: transpose + bf16
// ---------------------------------------------------------------------------
__global__ __launch_bounds__(256) void k_wprep(const float* __restrict__ W1,
                                               const float* __restrict__ W2,
                                               const float* __restrict__ W3,
                                               unsigned short* __restrict__ T1,
                                               unsigned short* __restrict__ T2,
                                               unsigned short* __restrict__ T3) {
  int idx = blockIdx.x * 256 + threadIdx.x;
  if (idx < 32768) {
    int n = idx >> 7, k = idx & 127;
    T1[idx] = f2bf(W1[(size_t)k * HID + n]);
  } else if (idx < 98304) {
    int j = idx - 32768;
    int n = j >> 8, k = j & 255;
    T2[j] = f2bf(W2[(size_t)k * HID + n]);
  } else if (idx < 131072) {
    int j = idx - 98304;
    int n = j >> 8, k = j & 255;
    T3[j] = f2bf((n < N_CLS) ? W3[(size_t)k * N_CLS + n] : 0.f);
  }
}

// ---------------------------------------------------------------------------
// quantize x: fp32 [N][128] -> signed int8 [N][64] ushort-packed, per-row scale
// folded into sw_x[i] = dinv[i] * scale_i. One wave per row.
// ---------------------------------------------------------------------------
__global__ __launch_bounds__(256) void k_qx(const float* __restrict__ x,
                                            const float* __restrict__ dinv,
                                            unsigned short* __restrict__ xq,
                                            float* __restrict__ sw_x) {
  int node = (blockIdx.x << 2) + (threadIdx.x >> 6);
  int lane = threadIdx.x & 63;
  if (node >= N_NODES) return;
  float2 v = ((const float2*)x)[(size_t)node * 64 + lane];
  float m = fmaxf(fabsf(v.x), fabsf(v.y));
  for (int off = 32; off; off >>= 1) m = fmaxf(m, __shfl_down(m, off));
  m = __shfl(m, 0);
  float inv = (m > 0.f) ? 127.f / m : 0.f;
  int q0 = __float2int_rn(v.x * inv);
  int q1 = __float2int_rn(v.y * inv);
  xq[(size_t)node * 64 + lane] = (unsigned short)((q0 & 0xff) | ((q1 & 0xff) << 8));
  if (lane == 0) sw_x[node] = dinv[node] * ((m > 0.f) ? m / 127.f : 0.f);
}

// ---------------------------------------------------------------------------
// int8 gather aggregation, 256-dim: 1 wave/node, 4 uint8/lane, unroll x8.
// sw is [2][N]: per-(row, col-half) scales; lane picks half by lane>=32.
// ---------------------------------------------------------------------------
__device__ __forceinline__ void up4u(unsigned v, float w,
                                     float& a0, float& a1, float& a2, float& a3) {
  a0 = fmaf((float)(v & 0xffu), w, a0);
  a1 = fmaf((float)((v >> 8) & 0xffu), w, a1);
  a2 = fmaf((float)((v >> 16) & 0xffu), w, a2);
  a3 = fmaf((float)(v >> 24), w, a3);
}

__global__ __launch_bounds__(256) void k_agg256i(const unsigned* __restrict__ tbl,  // [N][64]
                                                 uint2* __restrict__ out,           // [N][64]
                                                 const float* __restrict__ dinv,
                                                 const float* __restrict__ sw2,     // [2][N]
                                                 const int* __restrict__ row_start,
                                                 const int* __restrict__ csr_src) {
  int node = (blockIdx.x << 2) + (threadIdx.x >> 6);
  int lane = threadIdx.x & 63;
  if (node >= N_NODES) return;
  const unsigned* col = tbl + lane;
  const float* sw = sw2 + ((lane >= 32) ? N_NODES : 0);
  float d = dinv[node];
  float ws = sw[node];
  unsigned v0 = col[(size_t)node * 64];
  float a0 = 0.f, a1 = 0.f, a2 = 0.f, a3 = 0.f;
  up4u(v0, ws, a0, a1, a2, a3);
  int e = row_start[node], e1 = row_start[node + 1];
  for (; e + 8 <= e1; e += 8) {
    int i0 = csr_src[e],     i1 = csr_src[e + 1], i2 = csr_src[e + 2], i3 = csr_src[e + 3];
    int i4 = csr_src[e + 4], i5 = csr_src[e + 5], i6 = csr_src[e + 6], i7 = csr_src[e + 7];
    float w0 = sw[i0], w1 = sw[i1], w2 = sw[i2], w3 = sw[i3];
    float w4 = sw[i4], w5 = sw[i5], w6 = sw[i6], w7 = sw[i7];
    unsigned r0 = col[(size_t)i0 * 64], r1 = col[(size_t)i1 * 64];
    unsigned r2 = col[(size_t)i2 * 64], r3 = col[(size_t)i3 * 64];
    unsigned r4 = col[(size_t)i4 * 64], r5 = col[(size_t)i5 * 64];
    unsigned r6 = col[(size_t)i6 * 64], r7 = col[(size_t)i7 * 64];
    up4u(r0, w0, a0, a1, a2, a3);
    up4u(r1, w1, a0, a1, a2, a3);
    up4u(r2, w2, a0, a1, a2, a3);
    up4u(r3, w3, a0, a1, a2, a3);
    up4u(r4, w4, a0, a1, a2, a3);
    up4u(r5, w5, a0, a1, a2, a3);
    up4u(r6, w6, a0, a1, a2, a3);
    up4u(r7, w7, a0, a1, a2, a3);
  }
  for (; e < e1; e++) {
    int i0 = csr_src[e];
    float w0 = sw[i0];
    unsigned r0 = col[(size_t)i0 * 64];
    up4u(r0, w0, a0, a1, a2, a3);
  }
  a0 *= d; a1 *= d; a2 *= d; a3 *= d;
  uint2 o;
  o.x = f2bf(a0) | ((unsigned)f2bf(a1) << 16);
  o.y = f2bf(a2) | ((unsigned)f2bf(a3) << 16);
  out[(size_t)node * 64 + lane] = o;
}

// int8 gather aggregation, 128-dim: 2 int8/lane (ushort), unroll x8.
__global__ __launch_bounds__(256) void k_agg128i(const unsigned short* __restrict__ tbl,
                                                 unsigned* __restrict__ out,  // [N][64]
                                                 const float* __restrict__ dinv,
                                                 const float* __restrict__ sw,
                                                 const int* __restrict__ row_start,
                                                 const int* __restrict__ csr_src) {
  int node = (blockIdx.x << 2) + (threadIdx.x >> 6);
  int lane = threadIdx.x & 63;
  if (node >= N_NODES) return;
  const unsigned short* col = tbl + lane;
  float d = dinv[node];
  float ws = sw[node];
  unsigned short v0 = col[(size_t)node * 64];
  float a0 = (float)(signed char)(v0 & 0xff) * ws;
  float a1 = (float)(signed char)(v0 >> 8) * ws;
  int e = row_start[node], e1 = row_start[node + 1];
  for (; e + 8 <= e1; e += 8) {
    int i0 = csr_src[e],     i1 = csr_src[e + 1], i2 = csr_src[e + 2], i3 = csr_src[e + 3];
    int i4 = csr_src[e + 4], i5 = csr_src[e + 5], i6 = csr_src[e + 6], i7 = csr_src[e + 7];
    float w0 = sw[i0], w1 = sw[i1], w2 = sw[i2], w3 = sw[i3];
    float w4 = sw[i4], w5 = sw[i5], w6 = sw[i6], w7 = sw[i7];
    unsigned short r0 = col[(size_t)i0 * 64], r1 = col[(size_t)i1 * 64];
    unsigned short r2 = col[(size_t)i2 * 64], r3 = col[(size_t)i3 * 64];
    unsigned short r4 = col[(size_t)i4 * 64], r5 = col[(size_t)i5 * 64];
    unsigned short r6 = col[(size_t)i6 * 64], r7 = col[(size_t)i7 * 64];
    a0 = fmaf((float)(signed char)(r0 & 0xff), w0, a0);
    a1 = fmaf((float)(signed char)(r0 >> 8), w0, a1);
    a0 = fmaf((float)(signed char)(r1 & 0xff), w1, a0);
    a1 = fmaf((float)(signed char)(r1 >> 8), w1, a1);
    a0 = fmaf((float)(signed char)(r2 & 0xff), w2, a0);
    a1 = fmaf((float)(signed char)(r2 >> 8), w2, a1);
    a0 = fmaf((float)(signed char)(r3 & 0xff), w3, a0);
    a1 = fmaf((float)(signed char)(r3 >> 8), w3, a1);
    a0 = fmaf((float)(signed char)(r4 & 0xff), w4, a0);
    a1 = fmaf((float)(signed char)(r4 >> 8), w4, a1);
    a0 = fmaf((float)(signed char)(r5 & 0xff), w5, a0);
    a1 = fmaf((float)(signed char)(r5 >> 8), w5, a1);
    a0 = fmaf((float)(signed char)(r6 & 0xff), w6, a0);
    a1 = fmaf((float)(signed char)(r6 >> 8), w6, a1);
    a0 = fmaf((float)(signed char)(r7 & 0xff), w7, a0);
    a1 = fmaf((float)(signed char)(r7 >> 8), w7, a1);
  }
  for (; e < e1; e++) {
    int i0 = csr_src[e];
    float w0 = sw[i0];
    unsigned short r0 = col[(size_t)i0 * 64];
    a0 = fmaf((float)(signed char)(r0 & 0xff), w0, a0);
    a1 = fmaf((float)(signed char)(r0 >> 8), w0, a1);
  }
  a0 *= d; a1 *= d;
  out[(size_t)node * 64 + lane] = f2bf(a0) | ((unsigned)f2bf(a1) << 16);
}

// ---------------------------------------------------------------------------
// MFMA GEMM (generic): C[M,ldc](bf16) = A[M,K](bf16) @ B[Npad,K]^T (+bias)(+relu)
// ---------------------------------------------------------------------------
__global__ __launch_bounds__(256) void k_gemm_mfma(const unsigned short* __restrict__ A,
                                                   int lda,
                                                   const unsigned short* __restrict__ B,
                                                   const float* __restrict__ bias,
                                                   unsigned short* __restrict__ C, int ldc,
                                                   int M, int K, int relu) {
  __shared__ alignas(16) unsigned short As[128][40];
  __shared__ alignas(16) unsigned short Bs[128][40];
  int tid = threadIdx.x;
  int lane = tid & 63, wv = tid >> 6;
  int wy = wv >> 1, wx = wv & 1;
  int row0 = blockIdx.x * 128, col0 = blockIdx.y * 128;

  f32x4 acc[4][4];
#pragma unroll
  for (int i = 0; i < 4; i++)
#pragma unroll
    for (int j = 0; j < 4; j++) acc[i][j] = 0.f;

  int sr0 = tid >> 2;
  int sc = (tid & 3) * 8;

  for (int k0 = 0; k0 < K; k0 += 32) {
#pragma unroll
    for (int it = 0; it < 2; it++) {
      int r = sr0 + it * 64;
      int gr = row0 + r;
      short8 va = 0;
      if (gr < M) va = *(const short8*)(A + (size_t)gr * lda + k0 + sc);
      *(short8*)&As[r][sc] = va;
      short8 vb = *(const short8*)(B + (size_t)(col0 + r) * K + k0 + sc);
      *(short8*)&Bs[r][sc] = vb;
    }
    __syncthreads();

    int ar = wy * 64 + (lane & 15);
    int br = wx * 64 + (lane & 15);
    int kk = (lane >> 4) * 8;
    short8 a[4], b[4];
#pragma unroll
    for (int mi = 0; mi < 4; mi++) a[mi] = *(const short8*)&As[ar + mi * 16][kk];
#pragma unroll
    for (int ni = 0; ni < 4; ni++) b[ni] = *(const short8*)&Bs[br + ni * 16][kk];
#pragma unroll
    for (int mi = 0; mi < 4; mi++)
#pragma unroll
      for (int ni = 0; ni < 4; ni++)
        acc[mi][ni] = __builtin_amdgcn_mfma_f32_16x16x32_bf16(a[mi], b[ni], acc[mi][ni], 0, 0, 0);
    __syncthreads();
  }

  int mbase = row0 + wy * 64;
  int nbase = col0 + wx * 64;
#pragma unroll
  for (int ni = 0; ni < 4; ni++) {
    int gc = nbase + ni * 16 + (lane & 15);
    if (gc >= ldc) continue;
    float bz = bias ? bias[gc] : 0.f;
#pragma unroll
    for (int mi = 0; mi < 4; mi++) {
      f32x4 v = acc[mi][ni];
#pragma unroll
      for (int r = 0; r < 4; r++) {
        int gr = mbase + mi * 16 + (lane >> 4) * 4 + r;
        if (gr < M) {
          float o = v[r] + bz;
          if (relu) o = fmaxf(o, 0.f);
          C[(size_t)gr * ldc + gc] = f2bf(o);
        }
      }
    }
  }
}

// ---------------------------------------------------------------------------
// Layer-1 GEMM with FUSED relu + uint8 quantization epilogue.
// Block = 128 rows x 128 cols = one col-half of the 256-wide output.
// Per-(row, half) scale: quad shfl-max -> LDS cross-wave combine ->
// sw_h[half][row] = dinv*max/255; bytes packed via LDS tile -> uint4 stores.
// ---------------------------------------------------------------------------
__global__ __launch_bounds__(256) void k_gemm_q(const unsigned short* __restrict__ A,
                                                int lda,
                                                const unsigned short* __restrict__ B,
                                                const float* __restrict__ bias,
                                                const float* __restrict__ dinv,
                                                unsigned* __restrict__ hq,   // [N][64] uints
                                                float* __restrict__ sw_h,    // [2][N]
                                                int M, int K) {
  __shared__ alignas(16) unsigned short As[128][40];
  __shared__ alignas(16) unsigned short Bs[128][40];
  __shared__ float rmax[128][2];
  __shared__ float rscale[128];
  __shared__ alignas(16) unsigned char qtile[128][128];
  int tid = threadIdx.x;
  int lane = tid & 63, wv = tid >> 6;
  int wy = wv >> 1, wx = wv & 1;
  int quad = lane >> 4;
  int row0 = blockIdx.x * 128, col0 = blockIdx.y * 128;
  int half = blockIdx.y;

  f32x4 acc[4][4];
#pragma unroll
  for (int i = 0; i < 4; i++)
#pragma unroll
    for (int j = 0; j < 4; j++) acc[i][j] = 0.f;

  int sr0 = tid >> 2;
  int sc = (tid & 3) * 8;

  for (int k0 = 0; k0 < K; k0 += 32) {
#pragma unroll
    for (int it = 0; it < 2; it++) {
      int r = sr0 + it * 64;
      int gr = row0 + r;
      short8 va = 0;
      if (gr < M) va = *(const short8*)(A + (size_t)gr * lda + k0 + sc);
      *(short8*)&As[r][sc] = va;
      short8 vb = *(const short8*)(B + (size_t)(col0 + r) * K + k0 + sc);
      *(short8*)&Bs[r][sc] = vb;
    }
    __syncthreads();

    int ar = wy * 64 + (lane & 15);
    int br = wx * 64 + (lane & 15);
    int kk = quad * 8;
    short8 a[4], b[4];
#pragma unroll
    for (int mi = 0; mi < 4; mi++) a[mi] = *(const short8*)&As[ar + mi * 16][kk];
#pragma unroll
    for (int ni = 0; ni < 4; ni++) b[ni] = *(const short8*)&Bs[br + ni * 16][kk];
#pragma unroll
    for (int mi = 0; mi < 4; mi++)
#pragma unroll
      for (int ni = 0; ni < 4; ni++)
        acc[mi][ni] = __builtin_amdgcn_mfma_f32_16x16x32_bf16(a[mi], b[ni], acc[mi][ni], 0, 0, 0);
    __syncthreads();
  }

  // ---- epilogue: bias + relu ----
#pragma unroll
  for (int ni = 0; ni < 4; ni++) {
    int gc = col0 + wx * 64 + ni * 16 + (lane & 15);
    float bz = bias[gc];
#pragma unroll
    for (int mi = 0; mi < 4; mi++)
#pragma unroll
      for (int r = 0; r < 4; r++)
        acc[mi][ni][r] = fmaxf(acc[mi][ni][r] + bz, 0.f);
  }
  // per-row max (over this wave's 64 cols): in-lane over ni, then quad shfl
  float m16[4][4];
#pragma unroll
  for (int mi = 0; mi < 4; mi++)
#pragma unroll
    for (int r = 0; r < 4; r++)
      m16[mi][r] = fmaxf(fmaxf(acc[mi][0][r], acc[mi][1][r]),
                         fmaxf(acc[mi][2][r], acc[mi][3][r]));
#pragma unroll
  for (int st = 1; st < 16; st <<= 1)
#pragma unroll
    for (int mi = 0; mi < 4; mi++)
#pragma unroll
      for (int r = 0; r < 4; r++)
        m16[mi][r] = fmaxf(m16[mi][r], __shfl_xor(m16[mi][r], st));
  {
    int i = lane & 15;
    int row = wy * 64 + (i >> 2) * 16 + quad * 4 + (i & 3);
    rmax[row][wx] = m16[i >> 2][i & 3];
  }
  __syncthreads();
  if (tid < 128) {
    float mx = fmaxf(rmax[tid][0], rmax[tid][1]);
    rscale[tid] = (mx > 0.f) ? 255.f / mx : 0.f;
    int grow = row0 + tid;
    if (grow < M) sw_h[half * N_NODES + grow] = dinv[grow] * ((mx > 0.f) ? mx / 255.f : 0.f);
  }
  __syncthreads();
  // quantize into LDS byte tile
#pragma unroll
  for (int ni = 0; ni < 4; ni++) {
    int c = wx * 64 + ni * 16 + (lane & 15);
#pragma unroll
    for (int mi = 0; mi < 4; mi++)
#pragma unroll
      for (int r = 0; r < 4; r++) {
        int row = wy * 64 + mi * 16 + quad * 4 + r;
        qtile[row][c] = (unsigned char)__float2uint_rn(acc[mi][ni][r] * rscale[row]);
      }
  }
  __syncthreads();
  // packed store: 128 rows x 32 uints = 1024 uint4, 4 per thread
  const uint4* qt = (const uint4*)qtile;
#pragma unroll
  for (int k = 0; k < 4; k++) {
    int idx = tid + k * 256;
    int row = idx >> 3, p = idx & 7;
    int grow = row0 + row;
    if (grow < M)
      *(uint4*)(hq + (size_t)grow * 64 + half * 32 + p * 4) = qt[idx];
  }
}

// ---------------------------------------------------------------------------
// layer-3: gather-agg over compact bf16 logits [N][64] + bias + log_softmax.
// 3 lane-groups x unroll 4 -> 12 concurrent 80B gathers.
// ---------------------------------------------------------------------------
__global__ __launch_bounds__(256) void k_agg40_lsm(const unsigned* __restrict__ in,  // [N][32]
                                                   float* __restrict__ out,
                                                   const float* __restrict__ dinv,
                                                   const int* __restrict__ row_start,
                                                   const int* __restrict__ csr_src,
                                                   const float* __restrict__ bias) {
  int node = (blockIdx.x << 2) + (threadIdx.x >> 6);
  int lane = threadIdx.x & 63;
  if (node >= N_NODES) return;
  int g = (lane >= 40) ? 2 : (lane >= 20 ? 1 : 0);
  int c = lane - g * 20;
  bool act3 = lane < 60;
  const unsigned* base = in + c;
  float d = dinv[node];
  float ws = (g == 0 && act3) ? d : 0.f;
  unsigned u0 = base[(size_t)node * 32];
  float a0 = bflo(u0) * ws, a1 = bfhi(u0) * ws;
  int e1 = row_start[node + 1];
  int eb = row_start[node];
  for (; eb + 12 <= e1; eb += 12) {
    int ea = eb + g, eb2 = eb + 3 + g, ec = eb + 6 + g, ed = eb + 9 + g;
    int ia = csr_src[ea], ib = csr_src[eb2], ic = csr_src[ec], id = csr_src[ed];
    float wa = act3 ? dinv[ia] : 0.f;
    float wb = act3 ? dinv[ib] : 0.f;
    float wc = act3 ? dinv[ic] : 0.f;
    float wd = act3 ? dinv[id] : 0.f;
    unsigned ra = base[(size_t)ia * 32];
    unsigned rb = base[(size_t)ib * 32];
    unsigned rc = base[(size_t)ic * 32];
    unsigned rd = base[(size_t)id * 32];
    a0 = fmaf(bflo(ra), wa, a0); a1 = fmaf(bfhi(ra), wa, a1);
    a0 = fmaf(bflo(rb), wb, a0); a1 = fmaf(bfhi(rb), wb, a1);
    a0 = fmaf(bflo(rc), wc, a0); a1 = fmaf(bfhi(rc), wc, a1);
    a0 = fmaf(bflo(rd), wd, a0); a1 = fmaf(bfhi(rd), wd, a1);
  }
  for (; eb < e1; eb += 3) {
    int ea = eb + g;
    bool v = act3 && (ea < e1);
    int ia = v ? csr_src[ea] : 0;
    float wa = v ? dinv[ia] : 0.f;
    unsigned ra = base[(size_t)ia * 32];
    a0 = fmaf(bflo(ra), wa, a0); a1 = fmaf(bfhi(ra), wa, a1);
  }
  a0 += __shfl(a0, c + 20) + __shfl(a0, c + 40);
  a1 += __shfl(a1, c + 20) + __shfl(a1, c + 40);
  bool act = lane < 20;
  float v0 = act ? a0 * d + bias[2 * lane] : -INFINITY;
  float v1 = act ? a1 * d + bias[2 * lane + 1] : -INFINITY;
  float m = fmaxf(v0, v1);
  for (int off = 32; off; off >>= 1) m = fmaxf(m, __shfl_down(m, off));
  m = __shfl(m, 0);
  float s = act ? expf(v0 - m) + expf(v1 - m) : 0.f;
  for (int off = 32; off; off >>= 1) s += __shfl_down(s, off);
  s = __shfl(s, 0);
  float lse = m + logf(s);
  if (act) {
    out[(size_t)node * N_CLS + 2 * lane] = v0 - lse;
    out[(size_t)node * N_CLS + 2 * lane + 1] = v1 - lse;
  }
}

// ---------------------------------------------------------------------------
extern "C" void kernel_launch(void* const* d_in, const int* in_sizes, int n_in,
                              void* d_out, int out_size, void* d_ws, size_t ws_size,
                              hipStream_t stream) {
  const float* x  = (const float*)d_in[0];
  const void*  ei = d_in[1];
  const float* W1 = (const float*)d_in[2];
  const float* b1 = (const float*)d_in[3];
  const float* W2 = (const float*)d_in[4];
  const float* b2 = (const float*)d_in[5];
  const float* W3 = (const float*)d_in[6];
  const float* b3 = (const float*)d_in[7];
  float* out = (float*)d_out;

  char* w = (char*)d_ws;
  auto alloc = [&](size_t bytes) {
    char* p = w;
    w += (bytes + 255) & ~(size_t)255;
    return p;
  };
  int*   flag          = (int*)alloc(64);
  int*   hist          = (int*)alloc((size_t)NBKT * 4);
  int*   bucket_start  = (int*)alloc((size_t)(NBKT + 1) * 4);
  int*   bucket_cursor = (int*)alloc((size_t)NBKT * 4);
  uint2* bpairs        = (uint2*)alloc((size_t)N_EDGES * 8);
  int*   csr_src       = (int*)alloc((size_t)N_EDGES * 4);
  int*   row_start     = (int*)alloc(((size_t)N_NODES + 1) * 4);
  float* dinv          = (float*)alloc((size_t)N_NODES * 4);
  float* sw_x          = (float*)alloc((size_t)N_NODES * 4);
  float* sw_h          = (float*)alloc((size_t)N_NODES * 2 * 4);   // [2][N]
  unsigned short* Wt1  = (unsigned short*)alloc((size_t)HID * IN_DIM * 2);
  unsigned short* Wt2  = (unsigned short*)alloc((size_t)HID * HID * 2);
  unsigned short* Wt3  = (unsigned short*)alloc((size_t)128 * HID * 2);
  unsigned short* xq   = (unsigned short*)alloc((size_t)N_NODES * 64 * 2);  // int8 x
  unsigned*       hq   = (unsigned*)alloc((size_t)N_NODES * 64 * 4);        // uint8 h1
  char* R0 = alloc((size_t)N_NODES * HID * 2);  // 51.2 MB
  char* R1 = alloc((size_t)N_NODES * HID * 2);  // 51.2 MB

  unsigned*       aggX  = (unsigned*)R0;        // [N][64] uints = [N,128] bf16
  uint2*          aggH1 = (uint2*)R0;           // [N][64] uint2 = [N,256] bf16 (over aggX)
  unsigned short* h2    = (unsigned short*)R1;  // [N,256] bf16
  unsigned short* C3    = (unsigned short*)R0;  // [N,64] bf16 (over aggH1)

  const int nb_w1 = (N_NODES + 3) / 4;          // 25000
  const int gm    = (N_NODES + 127) / 128;      // 782

  // CSR build
  k_pre0<<<1, 512, 0, stream>>>((const unsigned int*)ei, flag, hist);
  k_hist<<<NPB, 256, 0, stream>>>(ei, flag, hist);
  k_bscan<<<1, 512, 0, stream>>>(hist, bucket_start, bucket_cursor);
  k_part<<<NPB, 256, 0, stream>>>(ei, flag, bucket_cursor, bpairs);
  k_bsort<<<NBKT, 256, 0, stream>>>(bpairs, bucket_start, row_start, dinv, csr_src);

  // weight prep + x quantization (needs dinv)
  k_wprep<<<512, 256, 0, stream>>>(W1, W2, W3, Wt1, Wt2, Wt3);
  k_qx<<<nb_w1, 256, 0, stream>>>(x, dinv, xq, sw_x);

  // layer 1: agg_int8(x) @ W1 + b1, relu, fused uint8 quantization
  k_agg128i<<<nb_w1, 256, 0, stream>>>(xq, aggX, dinv, sw_x, row_start, csr_src);
  k_gemm_q<<<dim3(gm, 2), 256, 0, stream>>>((const unsigned short*)aggX, IN_DIM, Wt1, b1,
                                            dinv, hq, sw_h, N_NODES, IN_DIM);
  // layer 2: agg_int8(h1q) @ W2 + b2, relu
  k_agg256i<<<nb_w1, 256, 0, stream>>>(hq, aggH1, dinv, sw_h, row_start, csr_src);
  k_gemm_mfma<<<dim3(gm, 2), 256, 0, stream>>>((const unsigned short*)aggH1, HID, Wt2, b2,
                                               h2, HID, N_NODES, HID, 1);
  // layer 3: agg(h2 @ W3) + b3, log_softmax (bf16 logits path)
  k_gemm_mfma<<<dim3(gm, 1), 256, 0, stream>>>(h2, HID, Wt3, nullptr,
                                               C3, 64, N_NODES, HID, 0);
  k_agg40_lsm<<<nb_w1, 256, 0, stream>>>((const unsigned*)C3, out, dinv, row_start,
                                         csr_src, b3);
}